// Round 3
// 82.984 us; speedup vs baseline: 1.0041x; 1.0041x over previous
//
#include <hip/hip_runtime.h>

#define Bn 64
#define Tn 512
#define Ln 48
#define START_L 46
#define PAD_L 45
#define END_L 47
#define LSEG 16          // timesteps per segment
#define NSEG 8           // segments (= waves) per block; block = 1 chunk
#define NCHUNK (Tn / (LSEG * NSEG))   // 4 chunks per batch

typedef float f32x4 __attribute__((ext_vector_type(4)));
typedef short s16x4 __attribute__((ext_vector_type(4)));
// 16x16x16 bf16 MFMA: B-frag layout (col=lane&15, k=(lane>>4)*4+j) == C/D layout
// (col=lane&15, row=(lane>>4)*4+r)  ->  C output chains directly into B input.
#define MFMA16(a, b, c) __builtin_amdgcn_mfma_f32_16x16x16bf16_1k(a, b, c, 0, 0, 0)

__device__ __forceinline__ unsigned short f2bf(float x) {
    unsigned u = __float_as_uint(x);
    u += 0x7fffu + ((u >> 16) & 1u);
    return (unsigned short)(u >> 16);
}
// truncation pack: low16 = bf16_trunc(a), high16 = bf16_trunc(b); 1 v_perm_b32
__device__ __forceinline__ unsigned pkT(float a, float b) {
    return __builtin_amdgcn_perm(__float_as_uint(b), __float_as_uint(a), 0x07060302u);
}
__device__ __forceinline__ float bcast0(float x) {
    return __int_as_float(__builtin_amdgcn_readfirstlane(__float_as_int(x)));
}
// Schraudolph fast exp (see prior round notes): x=-10000 saturates to -0.0 == exp(-1e4)
__device__ __forceinline__ float sexp(float x) {
    return __int_as_float((int)fmaf(x, 12102203.0f, 1064866805.0f));
}
__device__ __forceinline__ float4 fexp4(float4 v) {
    float4 r; r.x = sexp(v.x); r.y = sexp(v.y); r.z = sexp(v.z); r.w = sexp(v.w);
    return r;
}

union U2 { unsigned u[2]; uint2 p; s16x4 v; };

// "Cstore" layout: 16x16 tile M held per-lane (c=lane&15, q=lane>>4), elem j = M[q*4+j][c].
// As B operand it feeds M; as A operand it feeds M^T; MFMA output is Cstore again.
// => mfma16(Cstore(U), Cstore(V)) = Cstore(U^T V)  (closed under iteration: zero LDS in scan).
// 48x48 via 3x3 tiles: Z[i][j] = sum_k mfma16(AT[k][i], Y[k][j]).
// Direction (derived from r0's VERIFIED A-frag values, not its comments):
//   even wave needs E^T*Y  => U = E   => AT elem j = E[k*16+q*4+j][i*16+c]
//   odd  wave needs E*Y    => U = E^T => AT elem j = E[i*16+c][k*16+q*4+j]

__device__ __forceinline__ float treeProd16(const uint2 (*TA)[64], const uint2 (*TBp)[64],
                                            uint2 (*TDst)[64], int lane) {
    s16x4 FA[9], FB[9];
    #pragma unroll
    for (int t = 0; t < 9; ++t) {
        U2 a; a.p = TA[t][lane];  FA[t] = a.v;
        U2 b; b.p = TBp[t][lane]; FB[t] = b.v;
    }
    const f32x4 z = {0.f, 0.f, 0.f, 0.f};
    f32x4 acc[3][3];
    #pragma unroll
    for (int i = 0; i < 3; ++i)
        #pragma unroll
        for (int j = 0; j < 3; ++j) {
            f32x4 a = MFMA16(FA[0 * 3 + i], FB[0 * 3 + j], z);
            a = MFMA16(FA[1 * 3 + i], FB[1 * 3 + j], a);
            acc[i][j] = MFMA16(FA[2 * 3 + i], FB[2 * 3 + j], a);
        }
    float r = bcast0(acc[0][0][0]);
    float rr = __builtin_amdgcn_rcpf(r);
    #pragma unroll
    for (int i = 0; i < 3; ++i)
        #pragma unroll
        for (int j = 0; j < 3; ++j) {
            U2 pu;
            pu.u[0] = pkT(acc[i][j][0] * rr, acc[i][j][1] * rr);
            pu.u[1] = pkT(acc[i][j][2] * rr, acc[i][j][3] * rr);
            TDst[i * 3 + j][lane] = pu.p;
        }
    return __logf(r);
}

// ---------- fused scan (in-register) + in-block tree fold: 256 blocks x 8 waves ----------
__global__ __launch_bounds__(512, 2) void scan_k(
        const float* __restrict__ scores,
        const float* __restrict__ trans,
        unsigned short* __restrict__ ws2M,
        float* __restrict__ ws2S,
        float* __restrict__ out) {
    const int b   = blockIdx.x & (Bn - 1);
    const int cid = blockIdx.x >> 6;          // 0..NCHUNK-1
    const int tid = threadIdx.x;
    const int w   = tid >> 6;
    const int lane = tid & 63;
    const int c = lane & 15;
    const int q = lane >> 4;

    __shared__ uint2 TD[NSEG][9][64];         // per-wave Cstore fragment dumps (36.9 KB)
    __shared__ float scl[16];

    const int s    = cid * NSEG + w;
    const int t0   = s * LSEG;
    const int tend = t0 + LSEG - 1;
    const int dirOdd = w & 1;                 // odd wave: transposed scan, t descending
    const float* sb = scores + (size_t)b * Tn * Ln;

    // static A tiles (see direction note above):
    // even: U=E   -> elem j = exp(trans[(kt*16+q*4+j)*Ln + it*16+c])
    // odd : U=E^T -> elem j = exp(trans[(it*16+c)*Ln + kt*16+q*4+j])
    s16x4 AT[3][3];
    #pragma unroll
    for (int kt = 0; kt < 3; ++kt)
        #pragma unroll
        for (int it = 0; it < 3; ++it) {
            U2 au;
            #pragma unroll
            for (int p2 = 0; p2 < 2; ++p2) {
                int a0 = q * 4 + 2 * p2;
                float tv0 = dirOdd ? trans[(it * 16 + c) * Ln + kt * 16 + a0]
                                   : trans[(kt * 16 + a0) * Ln + it * 16 + c];
                float tv1 = dirOdd ? trans[(it * 16 + c) * Ln + kt * 16 + a0 + 1]
                                   : trans[(kt * 16 + a0 + 1) * Ln + it * 16 + c];
                au.u[p2] = pkT(__expf(tv0), __expf(tv1));
            }
            AT[kt][it] = au.v;
        }

    // init state: even -> diag(esc_t0); odd -> identity  (Cstore fragments)
    s16x4 YB[3][3];
    #pragma unroll
    for (int k = 0; k < 3; ++k)
        #pragma unroll
        for (int j = 0; j < 3; ++j) {
            U2 yu; yu.u[0] = 0u; yu.u[1] = 0u;
            if (k == j && q == (c >> 2)) {
                unsigned short hv = dirOdd ? (unsigned short)0x3F80
                                           : f2bf(__expf(sb[(size_t)t0 * Ln + k * 16 + c]));
                yu.u[(c >> 1) & 1] = ((unsigned)hv) << ((c & 1) * 16);
            }
            YB[k][j] = yu.v;
        }

    // esc pipeline: round tau scales by esc(t0+1+tau) [even] / esc(tend-tau) [odd]
    float4 wA, wB, wC, rA, rB, rC;
    {
        int t1 = dirOdd ? tend : (t0 + 1);
        const float* rp = sb + (size_t)t1 * Ln;
        wA = fexp4(*(const float4*)(rp + q * 4));
        wB = fexp4(*(const float4*)(rp + 16 + q * 4));
        wC = fexp4(*(const float4*)(rp + 32 + q * 4));
        int t2 = dirOdd ? (tend - 1) : (t0 + 2);
        const float* rp2 = sb + (size_t)t2 * Ln;
        rA = *(const float4*)(rp2 + q * 4);
        rB = *(const float4*)(rp2 + 16 + q * 4);
        rC = *(const float4*)(rp2 + 32 + q * 4);
    }

    const f32x4 z = {0.f, 0.f, 0.f, 0.f};
    float Cs = 0.f;
    for (int tau = 0; tau < LSEG; ++tau) {
        int tp = dirOdd ? (tend - (tau + 2)) : (t0 + 3 + tau);
        if (tp < t0) tp = t0;
        if (tp > tend) tp = tend;
        const float* rp3 = sb + (size_t)tp * Ln;
        float4 nA = *(const float4*)(rp3 + q * 4);
        float4 nB = *(const float4*)(rp3 + 16 + q * 4);
        float4 nC = *(const float4*)(rp3 + 32 + q * 4);

        f32x4 acc[3][3];
        #pragma unroll
        for (int i = 0; i < 3; ++i)
            #pragma unroll
            for (int j = 0; j < 3; ++j) {
                f32x4 a = MFMA16(AT[0][i], YB[0][j], z);
                a = MFMA16(AT[1][i], YB[1][j], a);
                acc[i][j] = MFMA16(AT[2][i], YB[2][j], a);
            }

        float4 w0 = wA, w1 = wB, w2 = wC;
        if (!dirOdd && tau == LSEG - 1) {      // even scan: no trailing D
            w0.x = w0.y = w0.z = w0.w = 1.f; w1 = w0; w2 = w0;
        }
        if ((tau & 3) == 0) {                  // renorm every 4 rounds
            float r = bcast0(acc[0][0][0]);
            float rr = __builtin_amdgcn_rcpf(r);
            Cs += __logf(r);
            w0.x *= rr; w0.y *= rr; w0.z *= rr; w0.w *= rr;
            w1.x *= rr; w1.y *= rr; w1.z *= rr; w1.w *= rr;
            w2.x *= rr; w2.y *= rr; w2.z *= rr; w2.w *= rr;
        }
        // scale rows by D (+renorm) and truncate-pack: next-step B operands, in-register
        #pragma unroll
        for (int i = 0; i < 3; ++i) {
            float4 wi = (i == 0) ? w0 : (i == 1) ? w1 : w2;
            #pragma unroll
            for (int j = 0; j < 3; ++j) {
                U2 pu;
                pu.u[0] = pkT(acc[i][j][0] * wi.x, acc[i][j][1] * wi.y);
                pu.u[1] = pkT(acc[i][j][2] * wi.z, acc[i][j][3] * wi.w);
                YB[i][j] = pu.v;
            }
        }

        wA = fexp4(rA); wB = fexp4(rB); wC = fexp4(rC);
        rA = nA; rB = nB; rC = nC;
    }
    if (lane == 0) scl[w] = Cs;

    // one-shot dump of final segment matrix (Cstore bf16, 8 B/lane/tile)
    #pragma unroll
    for (int i = 0; i < 3; ++i)
        #pragma unroll
        for (int j = 0; j < 3; ++j) {
            U2 du; du.v = YB[i][j];
            TD[w][i * 3 + j][lane] = du.p;
        }
    __syncthreads();

    // tree level 1: G_i = S_{2i+1} S_{2i} (even i) / G_i^T (odd i) -> slot 2i
    if (w < 4) {
        int ia = (w & 1) ? (2 * w) : (2 * w + 1);
        int ib = (w & 1) ? (2 * w + 1) : (2 * w);
        float lg = treeProd16(TD[ia], TD[ib], TD[2 * w], lane);
        if (lane == 0) scl[8 + w] = lg;
    }
    __syncthreads();
    // level 2: K0 = H(G1^T, G0) -> slot0 ; K1^T = H(G2, G3^T) -> slot4
    if (w < 2) {
        float lg = treeProd16(TD[w ? 4 : 2], TD[w ? 6 : 0], TD[w ? 4 : 0], lane);
        if (lane == 0) scl[12 + w] = lg;
    }
    __syncthreads();
    // level 3: C = H(K1^T, K0) -> global (row-major) + total log-scale
    if (w == 0) {
        s16x4 FA[9], FB[9];
        #pragma unroll
        for (int t = 0; t < 9; ++t) {
            U2 a; a.p = TD[4][t][lane];  FA[t] = a.v;
            U2 bb; bb.p = TD[0][t][lane]; FB[t] = bb.v;
        }
        f32x4 pac[3][3];
        #pragma unroll
        for (int i = 0; i < 3; ++i)
            #pragma unroll
            for (int j = 0; j < 3; ++j) {
                f32x4 a = MFMA16(FA[0 * 3 + i], FB[0 * 3 + j], z);
                a = MFMA16(FA[1 * 3 + i], FB[1 * 3 + j], a);
                pac[i][j] = MFMA16(FA[2 * 3 + i], FB[2 * 3 + j], a);
            }
        float r = bcast0(pac[0][0][0]);
        float rr = __builtin_amdgcn_rcpf(r);
        float Ct = __logf(r);
        #pragma unroll
        for (int i2 = 0; i2 < 14; ++i2) Ct += scl[i2];
        unsigned short* mp = ws2M + (size_t)blockIdx.x * (Ln * Ln);
        #pragma unroll
        for (int mt = 0; mt < 3; ++mt)
            #pragma unroll
            for (int nt = 0; nt < 3; ++nt)
                #pragma unroll
                for (int r2 = 0; r2 < 4; ++r2)
                    mp[(mt * 16 + q * 4 + r2) * Ln + nt * 16 + c] = f2bf(pac[mt][nt][r2] * rr);
        if (lane == 0) ws2S[blockIdx.x] = Ct;
    }
    if (blockIdx.x == 0 && tid == 0) out[0] = 0.f;
}

// ------ fold 4 chunk matrices into vector (wave 0) + gold (4 waves) ---------
__global__ __launch_bounds__(256) void fin_k(
        const float* __restrict__ scores,
        const int* __restrict__ gold,
        const int* __restrict__ mask,
        const float* __restrict__ trans,
        const unsigned short* __restrict__ ws2M,
        const float* __restrict__ ws2S,
        float* __restrict__ out) {
    const int b = blockIdx.x;
    const int tid = threadIdx.x;
    const int wv = tid >> 6;
    const int lane = tid & 63;

    __shared__ float vB[64];
    __shared__ float gred[4];

    // ---- gold-path energy: 4 waves x 2 t's each
    float tgv = 0.0f;
    #pragma unroll
    for (int k = 0; k < 2; ++k) {
        int idx = b * Tn + tid + k * 256;
        if (mask[idx]) tgv += scores[(size_t)idx * Ln] + trans[gold[idx]];
    }
    #pragma unroll
    for (int off = 32; off > 0; off >>= 1) tgv += __shfl_down(tgv, off);
    if (lane == 0) gred[wv] = tgv;
    __syncthreads();
    if (tid == 0) {
        float s = gred[0] + gred[1] + gred[2] + gred[3];
        float vv = -s * (1.0f / Bn);
        if (b == 0) vv -= trans[START_L];        // t=0 gold term
        atomicAdd(out, vv);
    }

    // ---- vector fold on wave 0
    if (wv == 0) {
        const int j = (lane < Ln) ? lane : (Ln - 1);
        float v = (lane < Ln) ? __expf(trans[START_L * Ln + lane]) : 0.0f;
        float Ctot = 0.0f;

        uint4 rows[NCHUNK][6];
        #pragma unroll
        for (int s2 = 0; s2 < NCHUNK; ++s2) {
            const unsigned short* p = ws2M + (size_t)(s2 * Bn + b) * (Ln * Ln) + (size_t)j * Ln;
            #pragma unroll
            for (int k = 0; k < 6; ++k) rows[s2][k] = *(const uint4*)(p + k * 8);
        }

        #pragma unroll
        for (int s2 = 0; s2 < NCHUNK; ++s2) {
            float Cs = ws2S[s2 * Bn + b];
            if (lane < Ln) vB[lane] = v;

            float a0 = 0.f, a1 = 0.f, a2 = 0.f, a3 = 0.f;
            #pragma unroll
            for (int k2 = 0; k2 < 12; ++k2) {
                float4 vb = *(const float4*)&vB[k2 * 4];
                uint4 ch = rows[s2][k2 >> 1];
                unsigned d0 = (k2 & 1) ? ch.z : ch.x;
                unsigned d1 = (k2 & 1) ? ch.w : ch.y;
                float f0 = __uint_as_float(d0 << 16);
                float f1 = __uint_as_float(d0 & 0xffff0000u);
                float f2 = __uint_as_float(d1 << 16);
                float f3 = __uint_as_float(d1 & 0xffff0000u);
                a0 = fmaf(f0, vb.x, a0);
                a1 = fmaf(f1, vb.y, a1);
                a2 = fmaf(f2, vb.z, a2);
                a3 = fmaf(f3, vb.w, a3);
            }
            float accv = (a0 + a1) + (a2 + a3);

            float r = bcast0(accv);
            v = accv * __builtin_amdgcn_rcpf(r);
            Ctot += __logf(r) + Cs;
        }

        if (lane == END_L) {
            atomicAdd(out, (__logf(v) + Ctot) * (1.0f / Bn));
        }
    }
}

extern "C" void kernel_launch(void* const* d_in, const int* in_sizes, int n_in,
                              void* d_out, int out_size, void* d_ws, size_t ws_size,
                              hipStream_t stream) {
    const float* scores = (const float*)d_in[0];
    const int*   gold   = (const int*)d_in[1];
    const int*   mask   = (const int*)d_in[2];
    const float* trans  = (const float*)d_in[3];
    float* out = (float*)d_out;

    unsigned short* ws2M = (unsigned short*)d_ws;
    float* ws2S = (float*)((char*)d_ws + (size_t)Bn * NCHUNK * Ln * Ln * 2);

    scan_k<<<Bn * NCHUNK, 512, 0, stream>>>(scores, trans, ws2M, ws2S, out);
    fin_k<<<Bn, 256, 0, stream>>>(scores, gold, mask, trans, ws2M, ws2S, out);
}